// Round 7
// baseline (261.880 us; speedup 1.0000x reference)
//
#include <hip/hip_runtime.h>

typedef __bf16 bf16x8 __attribute__((ext_vector_type(8)));
typedef float f32x4 __attribute__((ext_vector_type(4)));
typedef unsigned short ushortx8 __attribute__((ext_vector_type(8)));
typedef unsigned short ushortx4 __attribute__((ext_vector_type(4)));

#if __has_builtin(__builtin_amdgcn_exp2f)
#define EXP2F(x) __builtin_amdgcn_exp2f(x)
#else
#define EXP2F(x) exp2f(x)
#endif
#if __has_builtin(__builtin_amdgcn_rcpf)
#define RCPF(x) __builtin_amdgcn_rcpf(x)
#else
#define RCPF(x) (1.0f / (x))
#endif

__device__ __forceinline__ unsigned short f2bf(float f) {
    unsigned int u = __builtin_bit_cast(unsigned int, f);
    u += 0x7fffu + ((u >> 16) & 1u);
    return (unsigned short)(u >> 16);
}

__device__ __forceinline__ bf16x8 ld_frag(const unsigned short* p) {
    return __builtin_bit_cast(bf16x8, *(const ushortx8*)p);
}

// pack two fp32 -> two bf16 in one instruction where available
__device__ __forceinline__ unsigned int pack_bf2(float lo, float hi) {
#if __has_builtin(__builtin_amdgcn_cvt_pk_bf16_f32)
    typedef __bf16 bf16x2 __attribute__((ext_vector_type(2)));
    bf16x2 v = __builtin_amdgcn_cvt_pk_bf16_f32(lo, hi);
    return __builtin_bit_cast(unsigned int, v);
#else
    unsigned int ulo = __builtin_bit_cast(unsigned int, lo) + 0x8000u;
    unsigned int uhi = __builtin_bit_cast(unsigned int, hi) + 0x8000u;
    return __builtin_amdgcn_perm(uhi, ulo, 0x07060302u);
#endif
}

// async global->LDS, 16B per lane, 1KB per wave-instruction.
// LDS dest = wave-uniform base + lane*16 (no per-lane scatter!).
__device__ __forceinline__ void async_cp16(const unsigned short* g, unsigned short* l) {
    __builtin_amdgcn_global_load_lds(
        (const __attribute__((address_space(1))) unsigned int*)g,
        (__attribute__((address_space(3))) unsigned int*)(unsigned long)(unsigned long long)(uintptr_t)
            reinterpret_cast<uintptr_t>(l),
        16, 0, 0);
}

// ---------------- fp32 -> bf16 conversion ----------------
__global__ void cvt_kernel(const float* __restrict__ src, unsigned short* __restrict__ dst, int n4) {
    int i = blockIdx.x * blockDim.x + threadIdx.x;
    if (i < n4) {
        float4 f = ((const float4*)src)[i];
        ushortx4 u = { f2bf(f.x), f2bf(f.y), f2bf(f.z), f2bf(f.w) };
        ((ushortx4*)dst)[i] = u;
    }
}

// 4 weight matrices (1M elems each) in one launch; dsts contiguous in ws
__global__ void cvt4_kernel(const float* __restrict__ s0, const float* __restrict__ s1,
                            const float* __restrict__ s2, const float* __restrict__ s3,
                            unsigned short* __restrict__ dst) {
    const float* src = (blockIdx.y == 0) ? s0 : (blockIdx.y == 1) ? s1 : (blockIdx.y == 2) ? s2 : s3;
    unsigned short* d = dst + (size_t)blockIdx.y * (1024 * 1024);
    int i = blockIdx.x * blockDim.x + threadIdx.x;
    float4 f = ((const float4*)src)[i];
    ushortx4 u = { f2bf(f.x), f2bf(f.y), f2bf(f.z), f2bf(f.w) };
    ((ushortx4*)d)[i] = u;
}

// ---------------- fused QKV GEMM (NT), double-buffered LDS, 1 barrier/iter ----------------
// grid (64, 24): y -> {matrix 0..2} x {n-tile 0..7}
// Prefetch K-step kt+32 into buf[1-cur] overlaps MFMA on buf[cur].
// Chunk-rotation swizzle keeps frag ds_read_b128 2-way (free).
// Q is pre-scaled by 0.125*log2(e) so attention works in exp2 domain.
__global__ __launch_bounds__(256, 3) void qkv_gemm(
    const unsigned short* __restrict__ xb,
    const unsigned short* __restrict__ wqb,
    const unsigned short* __restrict__ wkb,
    const unsigned short* __restrict__ wvb,
    unsigned short* __restrict__ q_ws,   // [B,H,T,D]
    unsigned short* __restrict__ k_ws,   // [B,H,T,D]
    unsigned short* __restrict__ v_ws)   // [B,H,D,T]
{
    __shared__ __align__(16) unsigned short A_lds[2][128 * 32];
    __shared__ __align__(16) unsigned short B_lds[2][128 * 32];

    const int tid = threadIdx.x;
    const int wv = tid >> 6;
    const int lane = tid & 63;
    const int quad = lane >> 4;
    const int l15 = lane & 15;
    const int wm = wv >> 1;  // 0..1
    const int wn = wv & 1;   // 0..1

    const int m0 = blockIdx.x * 128;
    const int mat = blockIdx.y >> 3;
    const int n0 = (blockIdx.y & 7) * 128;
    const unsigned short* wb = (mat == 0) ? wqb : (mat == 1 ? wkb : wvb);

    // staging: lane owns LDS slot (row=lane>>2, pchunk=lane&3); fetch global
    // chunk c with (c + (row>>1))&3 == pchunk -> c = (p - (lane>>3))&3
    const int srow = lane >> 2;
    const int scol = ((((lane & 3) - ((lane >> 3) & 3)) & 3) * 8);
    const unsigned short* ag0 = xb + (size_t)(m0 + wv * 32 + srow) * 1024 + scol;
    const unsigned short* ag1 = ag0 + 16 * 1024;
    const unsigned short* bg0 = wb + (size_t)(n0 + wv * 32 + srow) * 1024 + scol;
    const unsigned short* bg1 = bg0 + 16 * 1024;
    const int lo0 = (wv * 32) * 32;
    const int lo1 = (wv * 32 + 16) * 32;

    // swizzled frag-read column: logical chunk = quad, physical = (quad + (row>>1))&3
    const int fcol = ((quad + (l15 >> 1)) & 3) * 8;

    f32x4 acc[4][4] = {};

    // prologue: stage kt=0 into buf 0
    async_cp16(ag0, A_lds[0] + lo0);
    async_cp16(ag1, A_lds[0] + lo1);
    async_cp16(bg0, B_lds[0] + lo0);
    async_cp16(bg1, B_lds[0] + lo1);
    __builtin_amdgcn_s_waitcnt(0x0F70);  // vmcnt(0)
    __syncthreads();

    for (int i = 0; i < 32; ++i) {
        const int cur = i & 1, nxt = cur ^ 1;
        if (i < 31) {
            const int kt = (i + 1) * 32;
            async_cp16(ag0 + kt, A_lds[nxt] + lo0);
            async_cp16(ag1 + kt, A_lds[nxt] + lo1);
            async_cp16(bg0 + kt, B_lds[nxt] + lo0);
            async_cp16(bg1 + kt, B_lds[nxt] + lo1);
        }

        bf16x8 af[4], bf[4];
#pragma unroll
        for (int ii = 0; ii < 4; ++ii)
            af[ii] = ld_frag(A_lds[cur] + (wm * 64 + ii * 16 + l15) * 32 + fcol);
#pragma unroll
        for (int ii = 0; ii < 4; ++ii)
            bf[ii] = ld_frag(B_lds[cur] + (wn * 64 + ii * 16 + l15) * 32 + fcol);
#pragma unroll
        for (int ii = 0; ii < 4; ++ii)
#pragma unroll
            for (int jj = 0; jj < 4; ++jj)
                acc[ii][jj] = __builtin_amdgcn_mfma_f32_16x16x32_bf16(af[ii], bf[jj], acc[ii][jj], 0, 0, 0);

        __builtin_amdgcn_s_waitcnt(0x0F70);  // vmcnt(0): prefetch landed
        __syncthreads();                     // everyone done reading cur + sees nxt
    }

    const float qscale = 0.125f * 1.4426950408889634f;
    const int mbase = m0 + wm * 64;
    const int nbase = n0 + wn * 64;
#pragma unroll
    for (int i = 0; i < 4; ++i) {
        const int mrow = mbase + i * 16 + quad * 4;  // +r, r=0..3 same b
        const int b = mrow >> 11;
        const int trow = mrow & 2047;
#pragma unroll
        for (int j = 0; j < 4; ++j) {
            const int nloc = nbase + j * 16 + l15;
            const int h = nloc >> 6, d = nloc & 63;
            if (mat == 2) {
                ushortx4 pk = { f2bf(acc[i][j][0]), f2bf(acc[i][j][1]),
                                f2bf(acc[i][j][2]), f2bf(acc[i][j][3]) };
                *(ushortx4*)&v_ws[(((size_t)(b * 16 + h)) * 64 + d) * 2048 + trow] = pk;
            } else {
                unsigned short* dst = (mat == 0) ? q_ws : k_ws;
                float sc = (mat == 0) ? qscale : 1.0f;
                size_t base = (((size_t)(b * 16 + h)) * 2048 + trow) * 64 + d;
                dst[base]       = f2bf(acc[i][j][0] * sc);
                dst[base + 64]  = f2bf(acc[i][j][1] * sc);
                dst[base + 128] = f2bf(acc[i][j][2] * sc);
                dst[base + 192] = f2bf(acc[i][j][3] * sc);
            }
        }
    }
}

// ---------------- flash attention, causal (S^T = K Q^T, no-max softmax) ----------------
// Register-prefetch pipeline: global loads for KV[j+1] are issued before the
// compute phase of j and consumed by ds_writes at the top of j+1 — staging
// latency fully overlaps compute. Swizzled unpadded K/V tiles (conflict-free
// frag reads), P via wave-private LDS rows (odd-dword stride) + lgkm fence.
// l = row-sum of P via MFMA with all-ones B. No running max (exp2-domain
// scores bounded by Cauchy-Schwarz, fp32 safe). Diagonal tile: wave-uniform
// work skip (~half of last iter).
// grid (64, 16): x -> b*16+h, y -> t-tile (reversed: heavy tiles first)
__global__ __launch_bounds__(256, 2) void attn_kernel(
    const unsigned short* __restrict__ q_ws,
    const unsigned short* __restrict__ k_ws,
    const unsigned short* __restrict__ v_ws,
    unsigned short* __restrict__ o_ws)   // [B*T, C] bf16
{
    __shared__ __align__(16) unsigned short K_lds[128 * 64];    // [s][d] swizzled chunks of 8
    __shared__ __align__(16) unsigned short Vt_lds[64 * 128];   // [d][s] swizzled chunks of 8
    __shared__ __align__(16) unsigned short P_lds[128][138];    // [t][s], 69-dw stride

    const int tid = threadIdx.x;
    const int wvid = tid >> 6, lane = tid & 63, quad = lane >> 4, l15 = lane & 15;
    const int bh = blockIdx.x;
    const int b = bh >> 4, h = bh & 15;
    const int bt = 15 - (int)blockIdx.y;
    const int t0 = bt * 128;

    const unsigned short* qb = q_ws + (size_t)bh * 2048 * 64;
    const unsigned short* kb = k_ws + (size_t)bh * 2048 * 64;
    const unsigned short* vb = v_ws + (size_t)bh * 64 * 2048;

    // all-ones bf16 B-fragment for MFMA row-sum (l computation)
    ushortx8 ones_u = { 0x3F80, 0x3F80, 0x3F80, 0x3F80, 0x3F80, 0x3F80, 0x3F80, 0x3F80 };
    const bf16x8 ones = __builtin_bit_cast(bf16x8, ones_u);

    // Q fragments (B-operand: n=t, k=d) live in registers for the whole block
    bf16x8 bq[2][2];
#pragma unroll
    for (int it = 0; it < 2; ++it)
#pragma unroll
        for (int kk = 0; kk < 2; ++kk)
            bq[it][kk] = ld_frag(qb + (size_t)(t0 + wvid * 32 + it * 16 + l15) * 64 + kk * 32 + quad * 8);

    f32x4 acc_o[2][4] = {};   // row t = quad*4+r, col d = id*16+l15
    f32x4 l_acc[2] = {};      // row t = quad*4+r (same indexing as acc_o)

    // staging lane coords (K: 8 rows x 8 chunks/wave-op; V: 4 rows x 16 chunks)
    const int krl = lane >> 3, kp = lane & 7;
    const int vrl = lane >> 4, vp = lane & 15;

    // prologue: load KV[0] into registers
    ushortx8 kreg[4], vreg[4];
#pragma unroll
    for (int u = 0; u < 4; ++u) {
        const int rl = u * 32 + wvid * 8 + krl;
        kreg[u] = *(const ushortx8*)(kb + (size_t)rl * 64 + (((kp - rl) & 7) * 8));
    }
#pragma unroll
    for (int u = 0; u < 4; ++u) {
        const int rl = u * 16 + wvid * 4 + vrl;
        vreg[u] = *(const ushortx8*)(vb + (size_t)rl * 2048 + (((vp - rl) & 15) * 8));
    }

    for (int j = 0; j <= bt; ++j) {
        const int s0 = j * 128;

        __syncthreads();   // previous iter's LDS reads all done
#pragma unroll
        for (int u = 0; u < 4; ++u) {
            const int rl = u * 32 + wvid * 8 + krl;
            *(ushortx8*)&K_lds[rl * 64 + kp * 8] = kreg[u];
        }
#pragma unroll
        for (int u = 0; u < 4; ++u) {
            const int rl = u * 16 + wvid * 4 + vrl;
            *(ushortx8*)&Vt_lds[rl * 128 + vp * 8] = vreg[u];
        }
        __syncthreads();

        if (j < bt) {   // prefetch KV[j+1]; completes during compute below
            const int s1 = s0 + 128;
#pragma unroll
            for (int u = 0; u < 4; ++u) {
                const int rl = u * 32 + wvid * 8 + krl;
                kreg[u] = *(const ushortx8*)(kb + (size_t)(s1 + rl) * 64 + (((kp - rl) & 7) * 8));
            }
#pragma unroll
            for (int u = 0; u < 4; ++u) {
                const int rl = u * 16 + wvid * 4 + vrl;
                vreg[u] = *(const ushortx8*)(vb + (size_t)rl * 2048 + s1 + (((vp - rl) & 15) * 8));
            }
        }

        // wave-uniform diagonal-tile work limits
        const int is_lim = (j == bt) ? (wvid * 2 + 2) : 8;
        const int kk_lim = (j == bt) ? (wvid + 1) : 4;

        // S^T = K Q^T : rows = s (128), cols = t (32 per wave)
        f32x4 sacc[2][8] = {};
#pragma unroll
        for (int is = 0; is < 8; ++is)
            if (is < is_lim) {
                const int rK = is * 16 + l15;
                bf16x8 k0 = ld_frag(K_lds + rK * 64 + (((quad + rK) & 7) * 8));
                bf16x8 k1 = ld_frag(K_lds + rK * 64 + (((4 + quad + rK) & 7) * 8));
                sacc[0][is] = __builtin_amdgcn_mfma_f32_16x16x32_bf16(k0, bq[0][0], sacc[0][is], 0, 0, 0);
                sacc[0][is] = __builtin_amdgcn_mfma_f32_16x16x32_bf16(k1, bq[0][1], sacc[0][is], 0, 0, 0);
                sacc[1][is] = __builtin_amdgcn_mfma_f32_16x16x32_bf16(k0, bq[1][0], sacc[1][is], 0, 0, 0);
                sacc[1][is] = __builtin_amdgcn_mfma_f32_16x16x32_bf16(k1, bq[1][1], sacc[1][is], 0, 0, 0);
            }

        // causal mask on diagonal tile only (exp2(-1e30) flushes to 0)
        if (j == bt) {
#pragma unroll
            for (int it = 0; it < 2; ++it) {
                const int tl = wvid * 32 + it * 16 + l15;
#pragma unroll
                for (int is = 0; is < 8; ++is)
                    if (is < is_lim)
#pragma unroll
                        for (int r = 0; r < 4; ++r) {
                            const int sl = is * 16 + quad * 4 + r;
                            if (sl > tl) sacc[it][is][r] = -1.0e30f;
                        }
            }
        }

        // P = exp2(S^T), store transposed into P_lds[t][s] (vector 8B writes)
#pragma unroll
        for (int it = 0; it < 2; ++it) {
            const int row = wvid * 32 + it * 16 + l15;
#pragma unroll
            for (int is = 0; is < 8; ++is)
                if (is < is_lim) {
                    float p0 = EXP2F(sacc[it][is][0]);
                    float p1 = EXP2F(sacc[it][is][1]);
                    float p2 = EXP2F(sacc[it][is][2]);
                    float p3 = EXP2F(sacc[it][is][3]);
                    uint2 pk = { pack_bf2(p0, p1), pack_bf2(p2, p3) };
                    *(uint2*)&P_lds[row][is * 16 + quad * 4] = pk;
                }
        }

        // each wave reads only the P rows it wrote -> lgkm drain, no barrier
        __threadfence_block();

        // O += P V, l += P 1 : A = P from LDS, B = V^T frags from swizzled LDS
#pragma unroll
        for (int kk = 0; kk < 4; ++kk)
            if (kk < kk_lim) {
                bf16x8 p0 = ld_frag(&P_lds[wvid * 32 + l15][kk * 32 + quad * 8]);
                bf16x8 p1 = ld_frag(&P_lds[wvid * 32 + 16 + l15][kk * 32 + quad * 8]);
                l_acc[0] = __builtin_amdgcn_mfma_f32_16x16x32_bf16(p0, ones, l_acc[0], 0, 0, 0);
                l_acc[1] = __builtin_amdgcn_mfma_f32_16x16x32_bf16(p1, ones, l_acc[1], 0, 0, 0);
#pragma unroll
                for (int id = 0; id < 4; ++id) {
                    const int rV = id * 16 + l15;
                    bf16x8 bv = ld_frag(Vt_lds + rV * 128 + (((kk * 4 + quad + rV) & 15) * 8));
                    acc_o[0][id] = __builtin_amdgcn_mfma_f32_16x16x32_bf16(p0, bv, acc_o[0][id], 0, 0, 0);
                    acc_o[1][id] = __builtin_amdgcn_mfma_f32_16x16x32_bf16(p1, bv, acc_o[1][id], 0, 0, 0);
                }
            }
    }

    // epilogue: out = acc_o / l; l_acc rows already match acc_o rows
#pragma unroll
    for (int it = 0; it < 2; ++it) {
        f32x4 rinv;
#pragma unroll
        for (int r = 0; r < 4; ++r) rinv[r] = RCPF(l_acc[it][r]);
#pragma unroll
        for (int id = 0; id < 4; ++id)
#pragma unroll
            for (int r = 0; r < 4; ++r) {
                int tg = t0 + wvid * 32 + it * 16 + quad * 4 + r;
                int c = h * 64 + id * 16 + l15;
                o_ws[(size_t)(b * 2048 + tg) * 1024 + c] = f2bf(acc_o[it][id][r] * rinv[r]);
            }
    }
}

// ---------------- output projection (NT) -> fp32, double-buffered ----------------
__global__ __launch_bounds__(256, 3) void out_gemm(
    const unsigned short* __restrict__ ob,
    const unsigned short* __restrict__ wob,
    float* __restrict__ out)
{
    __shared__ __align__(16) unsigned short A_lds[2][128 * 32];
    __shared__ __align__(16) unsigned short B_lds[2][128 * 32];

    const int tid = threadIdx.x;
    const int wv = tid >> 6;
    const int lane = tid & 63;
    const int quad = lane >> 4;
    const int l15 = lane & 15;
    const int wm = wv >> 1;
    const int wn = wv & 1;

    const int m0 = blockIdx.x * 128;
    const int n0 = blockIdx.y * 128;

    const int srow = lane >> 2;
    const int scol = ((((lane & 3) - ((lane >> 3) & 3)) & 3) * 8);
    const unsigned short* ag0 = ob + (size_t)(m0 + wv * 32 + srow) * 1024 + scol;
    const unsigned short* ag1 = ag0 + 16 * 1024;
    const unsigned short* bg0 = wob + (size_t)(n0 + wv * 32 + srow) * 1024 + scol;
    const unsigned short* bg1 = bg0 + 16 * 1024;
    const int lo0 = (wv * 32) * 32;
    const int lo1 = (wv * 32 + 16) * 32;

    const int fcol = ((quad + (l15 >> 1)) & 3) * 8;

    f32x4 acc[4][4] = {};

    async_cp16(ag0, A_lds[0] + lo0);
    async_cp16(ag1, A_lds[0] + lo1);
    async_cp16(bg0, B_lds[0] + lo0);
    async_cp16(bg1, B_lds[0] + lo1);
    __builtin_amdgcn_s_waitcnt(0x0F70);  // vmcnt(0)
    __syncthreads();

    for (int i = 0; i < 32; ++i) {
        const int cur = i & 1, nxt = cur ^ 1;
        if (i < 31) {
            const int kt = (i + 1) * 32;
            async_cp16(ag0 + kt, A_lds[nxt] + lo0);
            async_cp16(ag1 + kt, A_lds[nxt] + lo1);
            async_cp16(bg0 + kt, B_lds[nxt] + lo0);
            async_cp16(bg1 + kt, B_lds[nxt] + lo1);
        }

        bf16x8 af[4], bf[4];
#pragma unroll
        for (int ii = 0; ii < 4; ++ii)
            af[ii] = ld_frag(A_lds[cur] + (wm * 64 + ii * 16 + l15) * 32 + fcol);
#pragma unroll
        for (int ii = 0; ii < 4; ++ii)
            bf[ii] = ld_frag(B_lds[cur] + (wn * 64 + ii * 16 + l15) * 32 + fcol);
#pragma unroll
        for (int ii = 0; ii < 4; ++ii)
#pragma unroll
            for (int jj = 0; jj < 4; ++jj)
                acc[ii][jj] = __builtin_amdgcn_mfma_f32_16x16x32_bf16(af[ii], bf[jj], acc[ii][jj], 0, 0, 0);

        __builtin_amdgcn_s_waitcnt(0x0F70);  // vmcnt(0)
        __syncthreads();
    }

    const int mbase = m0 + wm * 64;
    const int nbase = n0 + wn * 64;
#pragma unroll
    for (int i = 0; i < 4; ++i) {
        const int mrow = mbase + i * 16 + quad * 4;
#pragma unroll
        for (int j = 0; j < 4; ++j) {
            const int ncol = nbase + j * 16 + l15;
            float* dst = out + (size_t)mrow * 1024 + ncol;
            dst[0]        = acc[i][j][0];
            dst[1024]     = acc[i][j][1];
            dst[2048]     = acc[i][j][2];
            dst[3072]     = acc[i][j][3];
        }
    }
}

extern "C" void kernel_launch(void* const* d_in, const int* in_sizes, int n_in,
                              void* d_out, int out_size, void* d_ws, size_t ws_size,
                              hipStream_t stream) {
    const float* x  = (const float*)d_in[0];
    const float* wq = (const float*)d_in[1];
    const float* wk = (const float*)d_in[2];
    const float* wv = (const float*)d_in[3];
    const float* wo = (const float*)d_in[4];
    float* out = (float*)d_out;

    unsigned short* ws = (unsigned short*)d_ws;
    unsigned short* xb   = ws;
    unsigned short* wqb  = xb  + (size_t)8192 * 1024;
    unsigned short* wkb  = wqb + (size_t)1024 * 1024;
    unsigned short* wvb  = wkb + (size_t)1024 * 1024;
    unsigned short* wob  = wvb + (size_t)1024 * 1024;
    unsigned short* q_ws = wob + (size_t)1024 * 1024;
    unsigned short* k_ws = q_ws + (size_t)8192 * 1024;
    unsigned short* v_ws = k_ws + (size_t)8192 * 1024;
    unsigned short* o_ws = v_ws + (size_t)8192 * 1024;

    int n4 = (8192 * 1024) / 4;
    cvt_kernel<<<(n4 + 255) / 256, 256, 0, stream>>>(x, xb, n4);
    cvt4_kernel<<<dim3(1024, 4), 256, 0, stream>>>(wq, wk, wv, wo, wqb);

    qkv_gemm<<<dim3(64, 24), 256, 0, stream>>>(xb, wqb, wkb, wvb, q_ws, k_ws, v_ws);
    attn_kernel<<<dim3(64, 16), 256, 0, stream>>>(q_ws, k_ws, v_ws, o_ws);
    out_gemm<<<dim3(64, 8), 256, 0, stream>>>(o_ws, wob, out);
}

// Round 8
// 237.613 us; speedup vs baseline: 1.1021x; 1.1021x over previous
//
#include <hip/hip_runtime.h>

typedef __bf16 bf16x8 __attribute__((ext_vector_type(8)));
typedef float f32x4 __attribute__((ext_vector_type(4)));
typedef unsigned short ushortx8 __attribute__((ext_vector_type(8)));
typedef unsigned short ushortx4 __attribute__((ext_vector_type(4)));

#if __has_builtin(__builtin_amdgcn_exp2f)
#define EXP2F(x) __builtin_amdgcn_exp2f(x)
#else
#define EXP2F(x) exp2f(x)
#endif
#if __has_builtin(__builtin_amdgcn_rcpf)
#define RCPF(x) __builtin_amdgcn_rcpf(x)
#else
#define RCPF(x) (1.0f / (x))
#endif

__device__ __forceinline__ unsigned short f2bf(float f) {
    unsigned int u = __builtin_bit_cast(unsigned int, f);
    u += 0x7fffu + ((u >> 16) & 1u);
    return (unsigned short)(u >> 16);
}

__device__ __forceinline__ bf16x8 ld_frag(const unsigned short* p) {
    return __builtin_bit_cast(bf16x8, *(const ushortx8*)p);
}

// pack two fp32 -> two bf16 in one instruction where available
__device__ __forceinline__ unsigned int pack_bf2(float lo, float hi) {
#if __has_builtin(__builtin_amdgcn_cvt_pk_bf16_f32)
    typedef __bf16 bf16x2 __attribute__((ext_vector_type(2)));
    bf16x2 v = __builtin_amdgcn_cvt_pk_bf16_f32(lo, hi);
    return __builtin_bit_cast(unsigned int, v);
#else
    unsigned int ulo = __builtin_bit_cast(unsigned int, lo) + 0x8000u;
    unsigned int uhi = __builtin_bit_cast(unsigned int, hi) + 0x8000u;
    return __builtin_amdgcn_perm(uhi, ulo, 0x07060302u);
#endif
}

// async global->LDS, 16B per lane, 1KB per wave-instruction.
// LDS dest = wave-uniform base + lane*16 (no per-lane scatter!).
__device__ __forceinline__ void async_cp16(const unsigned short* g, unsigned short* l) {
    __builtin_amdgcn_global_load_lds(
        (const __attribute__((address_space(1))) unsigned int*)g,
        (__attribute__((address_space(3))) unsigned int*)(unsigned long)(unsigned long long)(uintptr_t)
            reinterpret_cast<uintptr_t>(l),
        16, 0, 0);
}

// ---------------- fp32 -> bf16 conversion ----------------
__global__ void cvt_kernel(const float* __restrict__ src, unsigned short* __restrict__ dst, int n4) {
    int i = blockIdx.x * blockDim.x + threadIdx.x;
    if (i < n4) {
        float4 f = ((const float4*)src)[i];
        ushortx4 u = { f2bf(f.x), f2bf(f.y), f2bf(f.z), f2bf(f.w) };
        ((ushortx4*)dst)[i] = u;
    }
}

// 4 weight matrices (1M elems each) in one launch; dsts contiguous in ws
__global__ void cvt4_kernel(const float* __restrict__ s0, const float* __restrict__ s1,
                            const float* __restrict__ s2, const float* __restrict__ s3,
                            unsigned short* __restrict__ dst) {
    const float* src = (blockIdx.y == 0) ? s0 : (blockIdx.y == 1) ? s1 : (blockIdx.y == 2) ? s2 : s3;
    unsigned short* d = dst + (size_t)blockIdx.y * (1024 * 1024);
    int i = blockIdx.x * blockDim.x + threadIdx.x;
    float4 f = ((const float4*)src)[i];
    ushortx4 u = { f2bf(f.x), f2bf(f.y), f2bf(f.z), f2bf(f.w) };
    ((ushortx4*)d)[i] = u;
}

// ---------------- fused QKV GEMM (NT): [8192,1024] x [1024,1024]^T x3 ----------------
// grid (64, 24): y -> {matrix 0..2} x {n-tile 0..7}
// m97 structure + chunk-rotation swizzle, 4 blocks/CU (16 KB LDS, 56 VGPR).
// Q is pre-scaled by 0.125*log2(e) so attention works in exp2 domain.
__global__ __launch_bounds__(256, 4) void qkv_gemm(
    const unsigned short* __restrict__ xb,
    const unsigned short* __restrict__ wqb,
    const unsigned short* __restrict__ wkb,
    const unsigned short* __restrict__ wvb,
    unsigned short* __restrict__ q_ws,   // [B,H,T,D]
    unsigned short* __restrict__ k_ws,   // [B,H,T,D]
    unsigned short* __restrict__ v_ws)   // [B,H,D,T]
{
    __shared__ __align__(16) unsigned short A_lds[128 * 32];
    __shared__ __align__(16) unsigned short B_lds[128 * 32];

    const int tid = threadIdx.x;
    const int wv = tid >> 6;
    const int lane = tid & 63;
    const int quad = lane >> 4;
    const int l15 = lane & 15;
    const int wm = wv >> 1;  // 0..1
    const int wn = wv & 1;   // 0..1

    const int m0 = blockIdx.x * 128;
    const int mat = blockIdx.y >> 3;
    const int n0 = (blockIdx.y & 7) * 128;
    const unsigned short* wb = (mat == 0) ? wqb : (mat == 1 ? wkb : wvb);

    // staging: lane owns LDS slot (row=lane>>2, pchunk=lane&3); fetch global
    // chunk c with (c + (row>>1))&3 == pchunk -> c = (p - (lane>>3))&3
    const int srow = lane >> 2;
    const int scol = ((((lane & 3) - ((lane >> 3) & 3)) & 3) * 8);
    const unsigned short* ag0 = xb + (size_t)(m0 + wv * 32 + srow) * 1024 + scol;
    const unsigned short* ag1 = ag0 + 16 * 1024;
    const unsigned short* bg0 = wb + (size_t)(n0 + wv * 32 + srow) * 1024 + scol;
    const unsigned short* bg1 = bg0 + 16 * 1024;
    unsigned short* la0 = A_lds + (wv * 32) * 32;
    unsigned short* la1 = A_lds + (wv * 32 + 16) * 32;
    unsigned short* lb0 = B_lds + (wv * 32) * 32;
    unsigned short* lb1 = B_lds + (wv * 32 + 16) * 32;

    // swizzled frag-read column: logical chunk = quad, physical = (quad + (row>>1))&3
    const int fcol = ((quad + (l15 >> 1)) & 3) * 8;

    f32x4 acc[4][4] = {};

    for (int kt = 0; kt < 1024; kt += 32) {
        __syncthreads();                 // prev iter's LDS reads done
        async_cp16(ag0 + kt, la0);
        async_cp16(ag1 + kt, la1);
        async_cp16(bg0 + kt, lb0);
        async_cp16(bg1 + kt, lb1);
        __builtin_amdgcn_s_waitcnt(0x0F70);  // vmcnt(0)
        __syncthreads();                 // all waves' stores landed

        bf16x8 af[4], bf[4];
#pragma unroll
        for (int i = 0; i < 4; ++i)
            af[i] = ld_frag(A_lds + (wm * 64 + i * 16 + l15) * 32 + fcol);
#pragma unroll
        for (int i = 0; i < 4; ++i)
            bf[i] = ld_frag(B_lds + (wn * 64 + i * 16 + l15) * 32 + fcol);
#pragma unroll
        for (int i = 0; i < 4; ++i)
#pragma unroll
            for (int j = 0; j < 4; ++j)
                acc[i][j] = __builtin_amdgcn_mfma_f32_16x16x32_bf16(af[i], bf[j], acc[i][j], 0, 0, 0);
    }

    const float qscale = 0.125f * 1.4426950408889634f;
    const int mbase = m0 + wm * 64;
    const int nbase = n0 + wn * 64;
#pragma unroll
    for (int i = 0; i < 4; ++i) {
        const int mrow = mbase + i * 16 + quad * 4;  // +r, r=0..3 same b
        const int b = mrow >> 11;
        const int trow = mrow & 2047;
#pragma unroll
        for (int j = 0; j < 4; ++j) {
            const int nloc = nbase + j * 16 + l15;
            const int h = nloc >> 6, d = nloc & 63;
            if (mat == 2) {
                ushortx4 pk = { f2bf(acc[i][j][0]), f2bf(acc[i][j][1]),
                                f2bf(acc[i][j][2]), f2bf(acc[i][j][3]) };
                *(ushortx4*)&v_ws[(((size_t)(b * 16 + h)) * 64 + d) * 2048 + trow] = pk;
            } else {
                unsigned short* dst = (mat == 0) ? q_ws : k_ws;
                float sc = (mat == 0) ? qscale : 1.0f;
                size_t base = (((size_t)(b * 16 + h)) * 2048 + trow) * 64 + d;
                dst[base]       = f2bf(acc[i][j][0] * sc);
                dst[base + 64]  = f2bf(acc[i][j][1] * sc);
                dst[base + 128] = f2bf(acc[i][j][2] * sc);
                dst[base + 192] = f2bf(acc[i][j][3] * sc);
            }
        }
    }
}

// ---------------- flash attention, causal (S^T = K Q^T, no-max softmax) ----------------
// s-tile = 64: LDS 36.8 KB -> 4 blocks/CU (16 waves) so barrier/latency
// stalls overlap across blocks. R4-proven staging: global->VGPR loads issued
// before barrier-1, ds_write, barrier-2, compute. Padded tiles ([.][72] =
// 36-dw stride: 2 dw/bank = free, 144 B rows keep b128 16B-aligned).
// No running max (exp2-domain scores bounded, fp32 safe); l = P*ones MFMA;
// P via wave-private LDS rows + lgkm fence. Wave-uniform skip of fully
// masked chunks.
// grid (64, 16): x -> b*16+h, y -> t-tile (reversed: heavy tiles first)
__global__ __launch_bounds__(256, 4) void attn_kernel(
    const unsigned short* __restrict__ q_ws,
    const unsigned short* __restrict__ k_ws,
    const unsigned short* __restrict__ v_ws,
    unsigned short* __restrict__ o_ws)   // [B*T, C] bf16
{
    __shared__ __align__(16) unsigned short K_lds[64][72];    // [s][d]
    __shared__ __align__(16) unsigned short Vt_lds[64][72];   // [d][s]
    __shared__ __align__(16) unsigned short P_lds[128][72];   // [t][s]

    const int tid = threadIdx.x;
    const int wvid = tid >> 6, lane = tid & 63, quad = lane >> 4, l15 = lane & 15;
    const int bh = blockIdx.x;
    const int b = bh >> 4, h = bh & 15;
    const int bt = 15 - (int)blockIdx.y;
    const int t0 = bt * 128;

    const unsigned short* qb = q_ws + (size_t)bh * 2048 * 64;
    const unsigned short* kb = k_ws + (size_t)bh * 2048 * 64;
    const unsigned short* vb = v_ws + (size_t)bh * 64 * 2048;

    // all-ones bf16 B-fragment for MFMA row-sum (l computation)
    ushortx8 ones_u = { 0x3F80, 0x3F80, 0x3F80, 0x3F80, 0x3F80, 0x3F80, 0x3F80, 0x3F80 };
    const bf16x8 ones = __builtin_bit_cast(bf16x8, ones_u);

    // Q fragments (B-operand: n=t, k=d) live in registers for the whole block
    bf16x8 bq[2][2];
#pragma unroll
    for (int it = 0; it < 2; ++it)
#pragma unroll
        for (int kk = 0; kk < 2; ++kk)
            bq[it][kk] = ld_frag(qb + (size_t)(t0 + wvid * 32 + it * 16 + l15) * 64 + kk * 32 + quad * 8);

    f32x4 acc_o[2][4] = {};   // row t = quad*4+r, col d = id*16+l15
    f32x4 l_acc[2] = {};      // row t = quad*4+r (same indexing as acc_o)

    // staging coords: 4 threads per 64-elem row, 16B x2 per thread
    const int kr = tid >> 2, kc = (tid & 3) * 16;
    const int tw_max = t0 + wvid * 32 + 31;   // last t row this wave owns

    const int jmax = 2 * bt + 1;
    for (int j = 0; j <= jmax; ++j) {
        const int s0 = j * 64;

        // stage K[s0..s0+63][0..63] and V^T[d][s0..s0+63] (current chunk)
        ushortx8 k0 = *(const ushortx8*)(kb + (size_t)(s0 + kr) * 64 + kc);
        ushortx8 k1 = *(const ushortx8*)(kb + (size_t)(s0 + kr) * 64 + kc + 8);
        ushortx8 v0 = *(const ushortx8*)(vb + (size_t)kr * 2048 + s0 + kc);
        ushortx8 v1 = *(const ushortx8*)(vb + (size_t)kr * 2048 + s0 + kc + 8);
        __syncthreads();   // previous iter's LDS reads all done
        *(ushortx8*)&K_lds[kr][kc]      = k0;
        *(ushortx8*)&K_lds[kr][kc + 8]  = k1;
        *(ushortx8*)&Vt_lds[kr][kc]     = v0;
        *(ushortx8*)&Vt_lds[kr][kc + 8] = v1;
        __syncthreads();

        // wave-uniform: skip chunks entirely above this wave's t range
        if (s0 > tw_max) continue;
        const bool diag = (s0 + 63 > t0 + wvid * 32);  // mask needed?

        // S^T = K Q^T : rows = s (64), cols = t (32 per wave)
        f32x4 sacc[2][4] = {};
#pragma unroll
        for (int is = 0; is < 4; ++is) {
            bf16x8 kf0 = ld_frag(&K_lds[is * 16 + l15][quad * 8]);
            bf16x8 kf1 = ld_frag(&K_lds[is * 16 + l15][32 + quad * 8]);
            sacc[0][is] = __builtin_amdgcn_mfma_f32_16x16x32_bf16(kf0, bq[0][0], sacc[0][is], 0, 0, 0);
            sacc[0][is] = __builtin_amdgcn_mfma_f32_16x16x32_bf16(kf1, bq[0][1], sacc[0][is], 0, 0, 0);
            sacc[1][is] = __builtin_amdgcn_mfma_f32_16x16x32_bf16(kf0, bq[1][0], sacc[1][is], 0, 0, 0);
            sacc[1][is] = __builtin_amdgcn_mfma_f32_16x16x32_bf16(kf1, bq[1][1], sacc[1][is], 0, 0, 0);
        }

        // causal mask (only when chunk straddles the diagonal for this wave)
        if (diag) {
#pragma unroll
            for (int it = 0; it < 2; ++it) {
                const int tl = t0 + wvid * 32 + it * 16 + l15;
#pragma unroll
                for (int is = 0; is < 4; ++is)
#pragma unroll
                    for (int r = 0; r < 4; ++r) {
                        const int sg = s0 + is * 16 + quad * 4 + r;
                        if (sg > tl) sacc[it][is][r] = -1.0e30f;
                    }
            }
        }

        // P = exp2(S^T), store transposed into P_lds[t][s-s0] (8B writes)
#pragma unroll
        for (int it = 0; it < 2; ++it) {
            const int row = wvid * 32 + it * 16 + l15;
#pragma unroll
            for (int is = 0; is < 4; ++is) {
                float p0 = EXP2F(sacc[it][is][0]);
                float p1 = EXP2F(sacc[it][is][1]);
                float p2 = EXP2F(sacc[it][is][2]);
                float p3 = EXP2F(sacc[it][is][3]);
                uint2 pk = { pack_bf2(p0, p1), pack_bf2(p2, p3) };
                *(uint2*)&P_lds[row][is * 16 + quad * 4] = pk;
            }
        }

        // each wave reads only the P rows it wrote -> lgkm drain, no barrier
        __threadfence_block();

        // O += P V, l += P 1 : A = P from LDS, B = V^T from LDS
#pragma unroll
        for (int kk = 0; kk < 2; ++kk) {
            bf16x8 p0 = ld_frag(&P_lds[wvid * 32 + l15][kk * 32 + quad * 8]);
            bf16x8 p1 = ld_frag(&P_lds[wvid * 32 + 16 + l15][kk * 32 + quad * 8]);
            l_acc[0] = __builtin_amdgcn_mfma_f32_16x16x32_bf16(p0, ones, l_acc[0], 0, 0, 0);
            l_acc[1] = __builtin_amdgcn_mfma_f32_16x16x32_bf16(p1, ones, l_acc[1], 0, 0, 0);
#pragma unroll
            for (int id = 0; id < 4; ++id) {
                bf16x8 bv = ld_frag(&Vt_lds[id * 16 + l15][kk * 32 + quad * 8]);
                acc_o[0][id] = __builtin_amdgcn_mfma_f32_16x16x32_bf16(p0, bv, acc_o[0][id], 0, 0, 0);
                acc_o[1][id] = __builtin_amdgcn_mfma_f32_16x16x32_bf16(p1, bv, acc_o[1][id], 0, 0, 0);
            }
        }
    }

    // epilogue: out = acc_o / l; l_acc rows already match acc_o rows
#pragma unroll
    for (int it = 0; it < 2; ++it) {
        f32x4 rinv;
#pragma unroll
        for (int r = 0; r < 4; ++r) rinv[r] = RCPF(l_acc[it][r]);
#pragma unroll
        for (int id = 0; id < 4; ++id)
#pragma unroll
            for (int r = 0; r < 4; ++r) {
                int tg = t0 + wvid * 32 + it * 16 + quad * 4 + r;
                int c = h * 64 + id * 16 + l15;
                o_ws[(size_t)(b * 2048 + tg) * 1024 + c] = f2bf(acc_o[it][id][r] * rinv[r]);
            }
    }
}

// ---------------- output projection (NT) -> fp32, m97 + swizzle, 4 blk/CU ----------------
__global__ __launch_bounds__(256, 4) void out_gemm(
    const unsigned short* __restrict__ ob,
    const unsigned short* __restrict__ wob,
    float* __restrict__ out)
{
    __shared__ __align__(16) unsigned short A_lds[128 * 32];
    __shared__ __align__(16) unsigned short B_lds[128 * 32];

    const int tid = threadIdx.x;
    const int wv = tid >> 6;
    const int lane = tid & 63;
    const int quad = lane >> 4;
    const int l15 = lane & 15;
    const int wm = wv >> 1;
    const int wn = wv & 1;

    const int m0 = blockIdx.x * 128;
    const int n0 = blockIdx.y * 128;

    const int srow = lane >> 2;
    const int scol = ((((lane & 3) - ((lane >> 3) & 3)) & 3) * 8);
    const unsigned short* ag0 = ob + (size_t)(m0 + wv * 32 + srow) * 1024 + scol;
    const unsigned short* ag1 = ag0 + 16 * 1024;
    const unsigned short* bg0 = wob + (size_t)(n0 + wv * 32 + srow) * 1024 + scol;
    const unsigned short* bg1 = bg0 + 16 * 1024;
    unsigned short* la0 = A_lds + (wv * 32) * 32;
    unsigned short* la1 = A_lds + (wv * 32 + 16) * 32;
    unsigned short* lb0 = B_lds + (wv * 32) * 32;
    unsigned short* lb1 = B_lds + (wv * 32 + 16) * 32;

    const int fcol = ((quad + (l15 >> 1)) & 3) * 8;

    f32x4 acc[4][4] = {};

    for (int kt = 0; kt < 1024; kt += 32) {
        __syncthreads();
        async_cp16(ag0 + kt, la0);
        async_cp16(ag1 + kt, la1);
        async_cp16(bg0 + kt, lb0);
        async_cp16(bg1 + kt, lb1);
        __builtin_amdgcn_s_waitcnt(0x0F70);  // vmcnt(0)
        __syncthreads();

        bf16x8 af[4], bf[4];
#pragma unroll
        for (int i = 0; i < 4; ++i)
            af[i] = ld_frag(A_lds + (wm * 64 + i * 16 + l15) * 32 + fcol);
#pragma unroll
        for (int i = 0; i < 4; ++i)
            bf[i] = ld_frag(B_lds + (wn * 64 + i * 16 + l15) * 32 + fcol);
#pragma unroll
        for (int i = 0; i < 4; ++i)
#pragma unroll
            for (int j = 0; j < 4; ++j)
                acc[i][j] = __builtin_amdgcn_mfma_f32_16x16x32_bf16(af[i], bf[j], acc[i][j], 0, 0, 0);
    }

    const int mbase = m0 + wm * 64;
    const int nbase = n0 + wn * 64;
#pragma unroll
    for (int i = 0; i < 4; ++i) {
        const int mrow = mbase + i * 16 + quad * 4;
#pragma unroll
        for (int j = 0; j < 4; ++j) {
            const int ncol = nbase + j * 16 + l15;
            float* dst = out + (size_t)mrow * 1024 + ncol;
            dst[0]        = acc[i][j][0];
            dst[1024]     = acc[i][j][1];
            dst[2048]     = acc[i][j][2];
            dst[3072]     = acc[i][j][3];
        }
    }
}

extern "C" void kernel_launch(void* const* d_in, const int* in_sizes, int n_in,
                              void* d_out, int out_size, void* d_ws, size_t ws_size,
                              hipStream_t stream) {
    const float* x  = (const float*)d_in[0];
    const float* wq = (const float*)d_in[1];
    const float* wk = (const float*)d_in[2];
    const float* wv = (const float*)d_in[3];
    const float* wo = (const float*)d_in[4];
    float* out = (float*)d_out;

    unsigned short* ws = (unsigned short*)d_ws;
    unsigned short* xb   = ws;
    unsigned short* wqb  = xb  + (size_t)8192 * 1024;
    unsigned short* wkb  = wqb + (size_t)1024 * 1024;
    unsigned short* wvb  = wkb + (size_t)1024 * 1024;
    unsigned short* wob  = wvb + (size_t)1024 * 1024;
    unsigned short* q_ws = wob + (size_t)1024 * 1024;
    unsigned short* k_ws = q_ws + (size_t)8192 * 1024;
    unsigned short* v_ws = k_ws + (size_t)8192 * 1024;
    unsigned short* o_ws = v_ws + (size_t)8192 * 1024;

    int n4 = (8192 * 1024) / 4;
    cvt_kernel<<<(n4 + 255) / 256, 256, 0, stream>>>(x, xb, n4);
    cvt4_kernel<<<dim3(1024, 4), 256, 0, stream>>>(wq, wk, wv, wo, wqb);

    qkv_gemm<<<dim3(64, 24), 256, 0, stream>>>(xb, wqb, wkb, wvb, q_ws, k_ws, v_ws);
    attn_kernel<<<dim3(64, 16), 256, 0, stream>>>(q_ws, k_ws, v_ws, o_ws);
    out_gemm<<<dim3(64, 8), 256, 0, stream>>>(o_ws, wob, out);
}